// Round 5
// baseline (400.614 us; speedup 1.0000x reference)
//
#include <hip/hip_runtime.h>
#include <cstdint>
#include <cstddef>

#define BDIM 8192
#define DDIM 512

typedef __bf16 bf16x8 __attribute__((ext_vector_type(8)));
typedef float f32x4 __attribute__((ext_vector_type(4)));

__device__ inline unsigned short f32_to_bf16(float f) {
    unsigned int u = __float_as_uint(f);
    u += 0x7FFF + ((u >> 16) & 1);   // RNE
    return (unsigned short)(u >> 16);
}

// One WAVE per row (no LDS, no barriers). 256 threads = 4 rows/block.
__global__ __launch_bounds__(256) void normalize_kernel(
    const float* __restrict__ a, const float* __restrict__ b,
    unsigned short* __restrict__ an, unsigned short* __restrict__ bn)
{
    const int lane = threadIdx.x & 63;
    const int row = blockIdx.x * 4 + (threadIdx.x >> 6);
    const float* src;
    unsigned short* dst;
    if (row < BDIM) {
        src = a + (size_t)row * DDIM;
        dst = an + (size_t)row * DDIM;
    } else {
        src = b + (size_t)(row - BDIM) * DDIM;
        dst = bn + (size_t)(row - BDIM) * DDIM;
    }
    const float4* s4 = (const float4*)src;
    float4 v0 = s4[lane];
    float4 v1 = s4[lane + 64];
    float ss = v0.x * v0.x + v0.y * v0.y + v0.z * v0.z + v0.w * v0.w
             + v1.x * v1.x + v1.y * v1.y + v1.z * v1.z + v1.w * v1.w;
#pragma unroll
    for (int m = 1; m < 64; m <<= 1) ss += __shfl_xor(ss, m);
    float inv = 1.0f / fmaxf(sqrtf(ss), 1e-8f);
    ushort4 o0, o1;
    o0.x = f32_to_bf16(v0.x * inv); o0.y = f32_to_bf16(v0.y * inv);
    o0.z = f32_to_bf16(v0.z * inv); o0.w = f32_to_bf16(v0.w * inv);
    o1.x = f32_to_bf16(v1.x * inv); o1.y = f32_to_bf16(v1.y * inv);
    o1.z = f32_to_bf16(v1.z * inv); o1.w = f32_to_bf16(v1.w * inv);
    ushort4* d4 = (ushort4*)dst;
    d4[lane] = o0;
    d4[lane + 64] = o1;
}

// ---------------------------------------------------------------------------
// R4 post-mortem: 4 structurally different schedules all land ~155-180us with
// no pipe >30% -> limiter is shared stream locality, not the loop. R5 change
// (single variable vs R4): T1 chunked XCD swizzle (bijective, 4096%8==0).
// Default round-robin gives each XCD ~12 interleaved A-panels and 512B-chunk
// writes scattered over ~1500 rows (DRAM burst-merge hostile; linear fill
// hits 6.5 TB/s, our writes ~1.9). Chunked: XCD k owns blocks [k*512,k*512+512)
// = 8 contiguous bm bands -> resident blocks share ~1.5 A-panels (L2-hot) and
// write one contiguous ~25MB row band per XCD.
// Everything else identical to the passing R4 kernel (128x128 tile, BK=64,
// 4 waves, 32KiB single-buffer LDS, chunk-XOR swizzle, 3 blk/CU, LDS-transpose
// epilogue + nontemporal dwordx4 stores + LDS-reduced atomics).
// ---------------------------------------------------------------------------
__global__ __launch_bounds__(256, 3) void gemm_fused_kernel(
    const unsigned short* __restrict__ an, const unsigned short* __restrict__ bn,
    const int* __restrict__ labels, float* __restrict__ cos_out,
    float* __restrict__ num, float* __restrict__ den)
{
    __shared__ __align__(16) char lds[32768];
    char* ldsC = (char*)lds;
    char* sA = ldsC;            // 128x64 bf16 = 16 KiB
    char* sB = ldsC + 16384;    // 128x64 bf16 = 16 KiB

    const int t = threadIdx.x;
    const int wid = t >> 6;        // 0..3
    const int lane = t & 63;
    const int quad = lane >> 4;
    const int lr = lane & 15;

    // T1 chunked XCD swizzle: dispatch index d round-robins XCDs; remap so
    // XCD k owns a contiguous 512-block range (8 bm bands).
    const int d = blockIdx.y * 64 + blockIdx.x;
    const int nl = (d & 7) * 512 + (d >> 3);
    const int bm = nl >> 6;        // 64 M-blocks
    const int bnb = nl & 63;       // 64 N-blocks

    const int wm = wid >> 1;       // rows wm*64..+63
    const int wn = wid & 1;        // cols wn*64..+63

    f32x4 acc[4][4] = {};

    // staging: thread t, call c moves 16B to LDS chunk li = c*256+t; that slot
    // holds global chunk (li&7)^(r&7) of tile row r = li>>3.
    unsigned gOffA[4], gOffB[4];
#pragma unroll
    for (int c = 0; c < 4; ++c) {
        int li = c * 256 + t;
        int r = li >> 3;
        int cch = (li & 7) ^ (r & 7);
        gOffA[c] = (unsigned)((bm * 128 + r) * (DDIM * 2) + cch * 16);
        gOffB[c] = (unsigned)((bnb * 128 + r) * (DDIM * 2) + cch * 16);
    }
    const char* aBase = (const char*)an;
    const char* bBase = (const char*)bn;

    for (int k0 = 0; k0 < DDIM; k0 += 64) {
#pragma unroll
        for (int c = 0; c < 4; ++c)
            __builtin_amdgcn_global_load_lds(
                (const __attribute__((address_space(1))) void*)(aBase + gOffA[c] + k0 * 2),
                (__attribute__((address_space(3))) void*)(sA + c * 4096 + t * 16),
                16, 0, 0);
#pragma unroll
        for (int c = 0; c < 4; ++c)
            __builtin_amdgcn_global_load_lds(
                (const __attribute__((address_space(1))) void*)(bBase + gOffB[c] + k0 * 2),
                (__attribute__((address_space(3))) void*)(sB + c * 4096 + t * 16),
                16, 0, 0);
        __syncthreads();   // compiler drains vmcnt before barrier (single-buffer needs it)

        bf16x8 af[4][2], bf[4][2];
#pragma unroll
        for (int mi = 0; mi < 4; ++mi)
#pragma unroll
            for (int kk = 0; kk < 2; ++kk) {
                int rp = wm * 64 + mi * 16 + lr;
                af[mi][kk] = *(const bf16x8*)(sA + rp * 128 +
                                              (((kk * 4 + quad) ^ (rp & 7)) << 4));
            }
#pragma unroll
        for (int ni = 0; ni < 4; ++ni)
#pragma unroll
            for (int kk = 0; kk < 2; ++kk) {
                int rp = wn * 64 + ni * 16 + lr;
                bf[ni][kk] = *(const bf16x8*)(sB + rp * 128 +
                                              (((kk * 4 + quad) ^ (rp & 7)) << 4));
            }
#pragma unroll
        for (int kk = 0; kk < 2; ++kk)
#pragma unroll
            for (int mi = 0; mi < 4; ++mi)
#pragma unroll
                for (int ni = 0; ni < 4; ++ni)
                    acc[mi][ni] = __builtin_amdgcn_mfma_f32_16x16x32_bf16(
                        af[mi][kk], bf[ni][kk], acc[mi][ni], 0, 0, 0);
        __syncthreads();   // reads done before next stage overwrites
    }

    // --- Epilogue: LDS-transposed coalesced stores + LDS-reduced atomics ---
    // C/D layout (m89/m91): col = lane&15, row = quad*4 + reg.
    const float INV_T = 1.0f / 0.07f;
    const int col0 = bnb * 128 + wn * 64 + lr;
    int lab_c[4];
#pragma unroll
    for (int ni = 0; ni < 4; ++ni) lab_c[ni] = labels[col0 + ni * 16];

    // wave-private 16x64 f32 patch, row stride 68 f32 (272 B): 16B-aligned,
    // quad-row bank offset 16 -> conflict-light scatter and b128 gather.
    float* patch = (float*)(ldsC + wid * 4352);
    float* part  = (float*)(ldsC + 17408);   // [wn][128][2] f32 partials

#pragma unroll
    for (int mi = 0; mi < 4; ++mi) {
        // 1) scatter acc fragment into patch (MFMA layout -> row-major)
#pragma unroll
        for (int ni = 0; ni < 4; ++ni)
#pragma unroll
            for (int r = 0; r < 4; ++r)
                patch[(quad * 4 + r) * 68 + ni * 16 + lr] = acc[mi][ni][r];

        // 2) fused exp row-sums -> LDS partials
#pragma unroll
        for (int r = 0; r < 4; ++r) {
            int rowL = wm * 64 + mi * 16 + quad * 4 + r;
            int lab_r = labels[bm * 128 + rowL];
            float dsum = 0.0f, nsum = 0.0f;
#pragma unroll
            for (int ni = 0; ni < 4; ++ni) {
                float e = __expf(acc[mi][ni][r] * INV_T);
                dsum += e;
                nsum += (lab_c[ni] == lab_r) ? e : 0.0f;
            }
#pragma unroll
            for (int m = 1; m < 16; m <<= 1) {
                dsum += __shfl_xor(dsum, m);
                nsum += __shfl_xor(nsum, m);
            }
            if (lr == 0) {
                float2 pv; pv.x = nsum; pv.y = dsum;
                *(float2*)&part[(size_t)(wn * 128 + rowL) * 2] = pv;
            }
        }

        // 3) coalesced nontemporal dwordx4 stores (4 rows x 256B per instr)
#pragma unroll
        for (int p = 0; p < 4; ++p) {
            f32x4 v = *(const f32x4*)&patch[(p * 4 + quad) * 68 + lr * 4];
            int row = bm * 128 + wm * 64 + mi * 16 + p * 4 + quad;
            f32x4* gp = (f32x4*)&cos_out[(size_t)row * BDIM + bnb * 128 + wn * 64 + lr * 4];
            __builtin_nontemporal_store(v, gp);
        }
    }

    __syncthreads();
    if (t < 128) {
        float2 p0 = *(float2*)&part[(size_t)(0 * 128 + t) * 2];
        float2 p1 = *(float2*)&part[(size_t)(1 * 128 + t) * 2];
        int row = bm * 128 + t;
        atomicAdd(&num[row], p0.x + p1.x);
        atomicAdd(&den[row], p0.y + p1.y);
    }
}

__global__ __launch_bounds__(1024) void loss_kernel(
    const float* __restrict__ num, const float* __restrict__ den,
    float* __restrict__ out)
{
    int t = threadIdx.x;
    float s = 0.0f;
#pragma unroll
    for (int i = 0; i < 8; ++i) {
        int idx = t + i * 1024;
        s += __logf(num[idx] / den[idx]);
    }
#pragma unroll
    for (int m = 1; m < 64; m <<= 1) s += __shfl_xor(s, m);
    __shared__ float red[16];
    if ((t & 63) == 0) red[t >> 6] = s;
    __syncthreads();
    if (t == 0) {
        float tot = 0.0f;
#pragma unroll
        for (int i = 0; i < 16; ++i) tot += red[i];
        out[0] = -tot / (float)BDIM;
    }
}

extern "C" void kernel_launch(void* const* d_in, const int* in_sizes, int n_in,
                              void* d_out, int out_size, void* d_ws, size_t ws_size,
                              hipStream_t stream)
{
    const int* labels = (const int*)d_in[0];
    const float* fa = (const float*)d_in[1];
    const float* fb = (const float*)d_in[2];
    float* out = (float*)d_out;

    // ws: a_n bf16 (8 MB) | b_n bf16 (8 MB) | num f32 (32 KB) | den f32 (32 KB)
    unsigned short* an = (unsigned short*)d_ws;
    unsigned short* bn = an + (size_t)BDIM * DDIM;
    float* num = (float*)(bn + (size_t)BDIM * DDIM);
    float* den = num + BDIM;

    hipMemsetAsync(num, 0, 2 * BDIM * sizeof(float), stream);  // ws is poisoned each call
    normalize_kernel<<<4096, 256, 0, stream>>>(fa, fb, an, bn);
    dim3 grid(64, 64);
    gemm_fused_kernel<<<grid, 256, 0, stream>>>(an, bn, labels, out + 1, num, den);
    loss_kernel<<<1, 1024, 0, stream>>>(num, den, out);
}

// Round 6
// 379.368 us; speedup vs baseline: 1.0560x; 1.0560x over previous
//
#include <hip/hip_runtime.h>
#include <cstdint>
#include <cstddef>

#define BDIM 8192
#define DDIM 512

typedef __bf16 bf16x8 __attribute__((ext_vector_type(8)));
typedef float f32x4 __attribute__((ext_vector_type(4)));

__device__ inline unsigned short f32_to_bf16(float f) {
    unsigned int u = __float_as_uint(f);
    u += 0x7FFF + ((u >> 16) & 1);   // RNE
    return (unsigned short)(u >> 16);
}

// One WAVE per row (no LDS, no barriers). 256 threads = 4 rows/block.
__global__ __launch_bounds__(256) void normalize_kernel(
    const float* __restrict__ a, const float* __restrict__ b,
    unsigned short* __restrict__ an, unsigned short* __restrict__ bn)
{
    const int lane = threadIdx.x & 63;
    const int row = blockIdx.x * 4 + (threadIdx.x >> 6);
    const float* src;
    unsigned short* dst;
    if (row < BDIM) {
        src = a + (size_t)row * DDIM;
        dst = an + (size_t)row * DDIM;
    } else {
        src = b + (size_t)(row - BDIM) * DDIM;
        dst = bn + (size_t)(row - BDIM) * DDIM;
    }
    const float4* s4 = (const float4*)src;
    float4 v0 = s4[lane];
    float4 v1 = s4[lane + 64];
    float ss = v0.x * v0.x + v0.y * v0.y + v0.z * v0.z + v0.w * v0.w
             + v1.x * v1.x + v1.y * v1.y + v1.z * v1.z + v1.w * v1.w;
#pragma unroll
    for (int m = 1; m < 64; m <<= 1) ss += __shfl_xor(ss, m);
    float inv = 1.0f / fmaxf(sqrtf(ss), 1e-8f);
    ushort4 o0, o1;
    o0.x = f32_to_bf16(v0.x * inv); o0.y = f32_to_bf16(v0.y * inv);
    o0.z = f32_to_bf16(v0.z * inv); o0.w = f32_to_bf16(v0.w * inv);
    o1.x = f32_to_bf16(v1.x * inv); o1.y = f32_to_bf16(v1.y * inv);
    o1.z = f32_to_bf16(v1.z * inv); o1.w = f32_to_bf16(v1.w * inv);
    ushort4* d4 = (ushort4*)dst;
    d4[lane] = o0;
    d4[lane + 64] = o1;
}

// ---------------------------------------------------------------------------
// R5 post-mortem: XCD swizzle -30us -> reverted (inputs are L3-resident; T1's
// mechanism doesn't apply). Base = R4 (best, 370us). Ledger: harness poisons
// ~205us fixed; gemm ~130-145us vs ~128us floor for the 268MB cos write at
// the observed ~2.1TB/s write-path rate. R6 attacks the remaining suspect:
// 1M device-scope atomicAdds into 64KB of num/den (each 128B line RMW'd
// ~2048x serially - invisible in pipe-% counters). Change vs R4 (surgical):
//  - blocks write deterministic float2 partials (1KB contiguous per block) to
//    part_g[bnb][8192]; NO global atomics, NO num/den memset.
//  - loss kernel: 8 blocks x 1024 thr reduce the 4MB partials (lane=row =>
//    coalesced 512B/wave per bnb slab), 8 f32 atomicAdds into out[0]
//    (out[0] zeroed by 4B memset; order-nondeterminism ~1e-7 << tol).
// Main loop & epilogue stores byte-identical to R4.
// ---------------------------------------------------------------------------
__global__ __launch_bounds__(256, 3) void gemm_fused_kernel(
    const unsigned short* __restrict__ an, const unsigned short* __restrict__ bn,
    const int* __restrict__ labels, float* __restrict__ cos_out,
    float2* __restrict__ part_g)
{
    __shared__ __align__(16) char lds[32768];
    char* ldsC = (char*)lds;
    char* sA = ldsC;            // 128x64 bf16 = 16 KiB
    char* sB = ldsC + 16384;    // 128x64 bf16 = 16 KiB

    const int t = threadIdx.x;
    const int wid = t >> 6;        // 0..3
    const int lane = t & 63;
    const int quad = lane >> 4;
    const int lr = lane & 15;
    const int bm = blockIdx.y;     // 64 M-blocks
    const int bnb = blockIdx.x;    // 64 N-blocks
    const int wm = wid >> 1;       // rows wm*64..+63
    const int wn = wid & 1;        // cols wn*64..+63

    f32x4 acc[4][4] = {};

    // staging: thread t, call c moves 16B to LDS chunk li = c*256+t; that slot
    // holds global chunk (li&7)^(r&7) of tile row r = li>>3.
    unsigned gOffA[4], gOffB[4];
#pragma unroll
    for (int c = 0; c < 4; ++c) {
        int li = c * 256 + t;
        int r = li >> 3;
        int cch = (li & 7) ^ (r & 7);
        gOffA[c] = (unsigned)((bm * 128 + r) * (DDIM * 2) + cch * 16);
        gOffB[c] = (unsigned)((bnb * 128 + r) * (DDIM * 2) + cch * 16);
    }
    const char* aBase = (const char*)an;
    const char* bBase = (const char*)bn;

    for (int k0 = 0; k0 < DDIM; k0 += 64) {
#pragma unroll
        for (int c = 0; c < 4; ++c)
            __builtin_amdgcn_global_load_lds(
                (const __attribute__((address_space(1))) void*)(aBase + gOffA[c] + k0 * 2),
                (__attribute__((address_space(3))) void*)(sA + c * 4096 + t * 16),
                16, 0, 0);
#pragma unroll
        for (int c = 0; c < 4; ++c)
            __builtin_amdgcn_global_load_lds(
                (const __attribute__((address_space(1))) void*)(bBase + gOffB[c] + k0 * 2),
                (__attribute__((address_space(3))) void*)(sB + c * 4096 + t * 16),
                16, 0, 0);
        __syncthreads();   // compiler drains vmcnt before barrier (single-buffer needs it)

        bf16x8 af[4][2], bf[4][2];
#pragma unroll
        for (int mi = 0; mi < 4; ++mi)
#pragma unroll
            for (int kk = 0; kk < 2; ++kk) {
                int rp = wm * 64 + mi * 16 + lr;
                af[mi][kk] = *(const bf16x8*)(sA + rp * 128 +
                                              (((kk * 4 + quad) ^ (rp & 7)) << 4));
            }
#pragma unroll
        for (int ni = 0; ni < 4; ++ni)
#pragma unroll
            for (int kk = 0; kk < 2; ++kk) {
                int rp = wn * 64 + ni * 16 + lr;
                bf[ni][kk] = *(const bf16x8*)(sB + rp * 128 +
                                              (((kk * 4 + quad) ^ (rp & 7)) << 4));
            }
#pragma unroll
        for (int kk = 0; kk < 2; ++kk)
#pragma unroll
            for (int mi = 0; mi < 4; ++mi)
#pragma unroll
                for (int ni = 0; ni < 4; ++ni)
                    acc[mi][ni] = __builtin_amdgcn_mfma_f32_16x16x32_bf16(
                        af[mi][kk], bf[ni][kk], acc[mi][ni], 0, 0, 0);
        __syncthreads();   // reads done before next stage overwrites
    }

    // --- Epilogue: LDS-transposed coalesced stores + deterministic partials ---
    // C/D layout (m89/m91): col = lane&15, row = quad*4 + reg.
    const float INV_T = 1.0f / 0.07f;
    const int col0 = bnb * 128 + wn * 64 + lr;
    int lab_c[4];
#pragma unroll
    for (int ni = 0; ni < 4; ++ni) lab_c[ni] = labels[col0 + ni * 16];

    // wave-private 16x64 f32 patch, row stride 68 f32 (272 B): 16B-aligned,
    // quad-row bank offset 16 -> conflict-light scatter and b128 gather.
    float* patch = (float*)(ldsC + wid * 4352);
    float* part  = (float*)(ldsC + 17408);   // [wn][128][2] f32 partials

#pragma unroll
    for (int mi = 0; mi < 4; ++mi) {
        // 1) scatter acc fragment into patch (MFMA layout -> row-major)
#pragma unroll
        for (int ni = 0; ni < 4; ++ni)
#pragma unroll
            for (int r = 0; r < 4; ++r)
                patch[(quad * 4 + r) * 68 + ni * 16 + lr] = acc[mi][ni][r];

        // 2) fused exp row-sums -> LDS partials
#pragma unroll
        for (int r = 0; r < 4; ++r) {
            int rowL = wm * 64 + mi * 16 + quad * 4 + r;
            int lab_r = labels[bm * 128 + rowL];
            float dsum = 0.0f, nsum = 0.0f;
#pragma unroll
            for (int ni = 0; ni < 4; ++ni) {
                float e = __expf(acc[mi][ni][r] * INV_T);
                dsum += e;
                nsum += (lab_c[ni] == lab_r) ? e : 0.0f;
            }
#pragma unroll
            for (int m = 1; m < 16; m <<= 1) {
                dsum += __shfl_xor(dsum, m);
                nsum += __shfl_xor(nsum, m);
            }
            if (lr == 0) {
                float2 pv; pv.x = nsum; pv.y = dsum;
                *(float2*)&part[(size_t)(wn * 128 + rowL) * 2] = pv;
            }
        }

        // 3) coalesced nontemporal dwordx4 stores (4 rows x 256B per instr)
#pragma unroll
        for (int p = 0; p < 4; ++p) {
            f32x4 v = *(const f32x4*)&patch[(p * 4 + quad) * 68 + lr * 4];
            int row = bm * 128 + wm * 64 + mi * 16 + p * 4 + quad;
            f32x4* gp = (f32x4*)&cos_out[(size_t)row * BDIM + bnb * 128 + wn * 64 + lr * 4];
            __builtin_nontemporal_store(v, gp);
        }
    }

    __syncthreads();
    // deterministic partial write: 1 KB contiguous per block, no atomics
    if (t < 128) {
        float2 p0 = *(float2*)&part[(size_t)(0 * 128 + t) * 2];
        float2 p1 = *(float2*)&part[(size_t)(1 * 128 + t) * 2];
        float2 pv; pv.x = p0.x + p1.x; pv.y = p0.y + p1.y;
        part_g[(size_t)bnb * BDIM + bm * 128 + t] = pv;
    }
}

// 8 blocks x 1024 threads; thread -> one row; 64 bnb-partials per row.
// Reads coalesced (consecutive lanes = consecutive rows within a bnb slab).
__global__ __launch_bounds__(1024) void loss_kernel(
    const float2* __restrict__ part_g, float* __restrict__ out)
{
    const int row = blockIdx.x * 1024 + threadIdx.x;
    float num = 0.0f, den = 0.0f;
#pragma unroll 8
    for (int b = 0; b < 64; ++b) {
        float2 p = part_g[(size_t)b * BDIM + row];
        num += p.x;
        den += p.y;
    }
    float s = __logf(num / den);
#pragma unroll
    for (int m = 1; m < 64; m <<= 1) s += __shfl_xor(s, m);
    __shared__ float red[16];
    const int t = threadIdx.x;
    if ((t & 63) == 0) red[t >> 6] = s;
    __syncthreads();
    if (t == 0) {
        float tot = 0.0f;
#pragma unroll
        for (int i = 0; i < 16; ++i) tot += red[i];
        atomicAdd(out, -tot / (float)BDIM);
    }
}

extern "C" void kernel_launch(void* const* d_in, const int* in_sizes, int n_in,
                              void* d_out, int out_size, void* d_ws, size_t ws_size,
                              hipStream_t stream)
{
    const int* labels = (const int*)d_in[0];
    const float* fa = (const float*)d_in[1];
    const float* fb = (const float*)d_in[2];
    float* out = (float*)d_out;

    // ws: a_n bf16 (8 MB) | b_n bf16 (8 MB) | part_g float2[64][8192] (4 MB)
    unsigned short* an = (unsigned short*)d_ws;
    unsigned short* bn = an + (size_t)BDIM * DDIM;
    float2* part_g = (float2*)(bn + (size_t)BDIM * DDIM);

    hipMemsetAsync(out, 0, sizeof(float), stream);  // out[0] accumulated by loss_kernel
    normalize_kernel<<<4096, 256, 0, stream>>>(fa, fb, an, bn);
    dim3 grid(64, 64);
    gemm_fused_kernel<<<grid, 256, 0, stream>>>(an, bn, labels, out + 1, part_g);
    loss_kernel<<<8, 1024, 0, stream>>>(part_g, out);
}